// Round 7
// baseline (328.034 us; speedup 1.0000x reference)
//
#include <hip/hip_runtime.h>

#define COST_CLASS 1.0f
#define COST_BBOX  5.0f
#define COST_GIOU  2.0f
#define EPS 1e-6f

// Problem constants (from setup_inputs): B=32, Q=300, C=11, T=3200
constexpr int kC  = 11;
constexpr int TPB = 64;    // 1 wave per block (800 t4 groups -> 13 blocks/row)
constexpr int NPT = 8;     // preds per inner chunk
constexpr int RB  = 4;     // row-blocks per thread -> 32 preds/thread

typedef float vf4 __attribute__((ext_vector_type(4)));
typedef float vf8 __attribute__((ext_vector_type(8)));

__device__ __forceinline__ float fast_rcp(float x) {
    return __builtin_amdgcn_rcpf(x);   // v_rcp_f32, ~1 ulp — fine vs 0.4 absmax threshold
}

// ---------------- Kernel A: softmax -> TRANSPOSED, pre-folded class cost ----
// probsT[c][n] = 2 - softmax(logits[n])[c]; the 2 folds the GIoU identity
//   (carea-uni)/(carea+EPS) == 1 - (uni+EPS)/(carea+EPS).
__global__ void softmax_probsT_kernel(const float* __restrict__ logits,
                                      float* __restrict__ probsT, int N) {
    int n = blockIdx.x * blockDim.x + threadIdx.x;
    if (n >= N) return;
    float v[kC];
    float m = -1e30f;
#pragma unroll
    for (int c = 0; c < kC; ++c) {
        v[c] = logits[n * kC + c];
        m = fmaxf(m, v[c]);
    }
    float s = 0.f;
#pragma unroll
    for (int c = 0; c < kC; ++c) {
        v[c] = __expf(v[c] - m);
        s += v[c];
    }
    float inv = fast_rcp(s);
#pragma unroll
    for (int c = 0; c < kC; ++c)
        probsT[(size_t)c * N + n] = fmaf(-v[c], inv, 2.0f);   // 2 - prob
}

// ---------------- Kernel B: production cost matrix (bit-identical to R6) ----
__global__ void cost_matrix_kernel(const float* __restrict__ probsT,      // [C,N] (=2-prob)
                                   const float* __restrict__ pred_boxes,  // [N,4] cxcywh
                                   const int*   __restrict__ labels,      // [T]
                                   const float* __restrict__ tboxes,      // [T,4] cxcywh
                                   float* __restrict__ out,               // [N,T]
                                   int N, int T) {
    int t4 = blockIdx.x * TPB + threadIdx.x;   // group of 4 targets
    if (t4 >= (T >> 2)) return;
    int tbase = t4 << 2;

    int4 labv = ((const int4*)labels)[t4];
    const int labs[4] = {labv.x, labv.y, labv.z, labv.w};
    float4 tb[4];
    float tx0[4], ty0[4], tx1[4], ty1[4], tarea[4];
#pragma unroll
    for (int j = 0; j < 4; ++j) {
        tb[j] = ((const float4*)tboxes)[tbase + j];
        tx0[j] = tb[j].x - 0.5f * tb[j].z;
        ty0[j] = tb[j].y - 0.5f * tb[j].w;
        tx1[j] = tb[j].x + 0.5f * tb[j].z;
        ty1[j] = tb[j].y + 0.5f * tb[j].w;
        tarea[j] = (tx1[j] - tx0[j]) * (ty1[j] - ty0[j]);
    }

#pragma unroll 1
    for (int rb = 0; rb < RB; ++rb) {
        int n0 = blockIdx.y * (NPT * RB) + rb * NPT;
        vf8 ccv[4];
#pragma unroll
        for (int j = 0; j < 4; ++j)
            ccv[j] = *(const vf8*)(probsT + (size_t)labs[j] * N + n0);

#pragma unroll
        for (int i = 0; i < NPT; ++i) {
            int n = n0 + i;
            float4 pb = ((const float4*)pred_boxes)[n];  // block-uniform -> s_load
            float p_x0 = pb.x - 0.5f * pb.z;
            float p_y0 = pb.y - 0.5f * pb.w;
            float p_x1 = pb.x + 0.5f * pb.z;
            float p_y1 = pb.y + 0.5f * pb.w;
            float p_area = (p_x1 - p_x0) * (p_y1 - p_y0);

            vf4 res;
#pragma unroll
            for (int j = 0; j < 4; ++j) {
                float cb = fabsf(pb.x - tb[j].x) + fabsf(pb.y - tb[j].y) +
                           fabsf(pb.z - tb[j].z) + fabsf(pb.w - tb[j].w);
                float lt_x = fmaxf(p_x0, tx0[j]), lt_y = fmaxf(p_y0, ty0[j]);
                float rb_x = fminf(p_x1, tx1[j]), rb_y = fminf(p_y1, ty1[j]);
                float iw = fmaxf(rb_x - lt_x, 0.f), ih = fmaxf(rb_y - lt_y, 0.f);
                float inter = iw * ih;
                float u = p_area + tarea[j] - inter + EPS;   // union + EPS
                float iou = inter * fast_rcp(u);
                float cx0 = fminf(p_x0, tx0[j]), cy0 = fminf(p_y0, ty0[j]);
                float cx1 = fmaxf(p_x1, tx1[j]), cy1 = fmaxf(p_y1, ty1[j]);
                float carea = (cx1 - cx0) * (cy1 - cy0);
                float g = u * fast_rcp(carea + EPS);         // (uni+EPS)/(carea+EPS)
                float rr = fmaf(COST_BBOX, cb, ccv[j][i]);
                rr = fmaf(-2.0f, iou, rr);
                res[j] = fmaf(-2.0f, g, rr);
            }
            *(vf4*)(out + (size_t)n * T + tbase) = res;
        }
    }
}

// ---------------- Diagnostics (workspace only, natural regalloc) ----------
// MODE 1 = full math, MODE 2 = store-only (same loads & store pattern, ~2
// VALU/element). REPEAT passes with per-pass CSE breaker + row rotation
// (writes stay coalesced: n is wave-uniform). Per-pass cost = dur / REPEAT.
template<int MODE, int REPEAT>
__global__ void cost_diag(const float* __restrict__ probsT,
                          const float* __restrict__ pred_boxes,
                          const int*   __restrict__ labels,
                          const float* __restrict__ tboxes,
                          float* __restrict__ out, int N, int T) {
    int t4 = blockIdx.x * TPB + threadIdx.x;
    if (t4 >= (T >> 2)) return;
    int tbase = t4 << 2;

    int4 labv = ((const int4*)labels)[t4];
    const int labs[4] = {labv.x, labv.y, labv.z, labv.w};
    float4 tb[4];
    float tx0[4], ty0[4], tx1[4], ty1[4], tarea[4];
#pragma unroll
    for (int j = 0; j < 4; ++j) {
        tb[j] = ((const float4*)tboxes)[tbase + j];
        tx0[j] = tb[j].x - 0.5f * tb[j].z;
        ty0[j] = tb[j].y - 0.5f * tb[j].w;
        tx1[j] = tb[j].x + 0.5f * tb[j].z;
        ty1[j] = tb[j].y + 0.5f * tb[j].w;
        tarea[j] = (tx1[j] - tx0[j]) * (ty1[j] - ty0[j]);
    }

#pragma unroll 1
    for (int r = 0; r < REPEAT; ++r) {
#pragma unroll 1
        for (int rb = 0; rb < RB; ++rb) {
            int n0 = blockIdx.y * (NPT * RB) + rb * NPT;
            vf8 ccv[4];
#pragma unroll
            for (int j = 0; j < 4; ++j)
                ccv[j] = *(const vf8*)(probsT + (size_t)labs[j] * N + n0);

#pragma unroll
            for (int i = 0; i < NPT; ++i) {
                int n = n0 + i;
                float4 pb = ((const float4*)pred_boxes)[n];
                pb.x += (float)r * 1e-20f;            // per-pass CSE breaker

                vf4 res;
                if constexpr (MODE == 2) {
                    // store-only: same inputs touched, trivial combine
#pragma unroll
                    for (int j = 0; j < 4; ++j)
                        res[j] = ccv[j][i] + tb[j].x + pb.x;
                } else {
                    float p_x0 = pb.x - 0.5f * pb.z;
                    float p_y0 = pb.y - 0.5f * pb.w;
                    float p_x1 = pb.x + 0.5f * pb.z;
                    float p_y1 = pb.y + 0.5f * pb.w;
                    float p_area = (p_x1 - p_x0) * (p_y1 - p_y0);
#pragma unroll
                    for (int j = 0; j < 4; ++j) {
                        float cb = fabsf(pb.x - tb[j].x) + fabsf(pb.y - tb[j].y) +
                                   fabsf(pb.z - tb[j].z) + fabsf(pb.w - tb[j].w);
                        float lt_x = fmaxf(p_x0, tx0[j]), lt_y = fmaxf(p_y0, ty0[j]);
                        float rb_x = fminf(p_x1, tx1[j]), rb_y = fminf(p_y1, ty1[j]);
                        float iw = fmaxf(rb_x - lt_x, 0.f), ih = fmaxf(rb_y - lt_y, 0.f);
                        float inter = iw * ih;
                        float u = p_area + tarea[j] - inter + EPS;
                        float iou = inter * fast_rcp(u);
                        float cx0 = fminf(p_x0, tx0[j]), cy0 = fminf(p_y0, ty0[j]);
                        float cx1 = fmaxf(p_x1, tx1[j]), cy1 = fmaxf(p_y1, ty1[j]);
                        float carea = (cx1 - cx0) * (cy1 - cy0);
                        float g = u * fast_rcp(carea + EPS);
                        float rr = fmaf(COST_BBOX, cb, ccv[j][i]);
                        rr = fmaf(-2.0f, iou, rr);
                        res[j] = fmaf(-2.0f, g, rr);
                    }
                }

                int nn = n + r * NPT;          // rotate rows/pass: defeats DSE,
                if (nn >= N) nn -= N;          // same footprint & coalescing
                *(vf4*)(out + (size_t)nn * T + tbase) = res;
            }
        }
    }
}

extern "C" void kernel_launch(void* const* d_in, const int* in_sizes, int n_in,
                              void* d_out, int out_size, void* d_ws, size_t ws_size,
                              hipStream_t stream) {
    const float* class_logits  = (const float*)d_in[0];  // [B,Q,C]
    const float* bbox_coords   = (const float*)d_in[1];  // [B,Q,4]
    const int*   target_labels = (const int*)d_in[2];    // [T]
    const float* target_boxes  = (const float*)d_in[3];  // [T,4]
    float* out = (float*)d_out;

    int N = in_sizes[0] / kC;  // 9600
    int T = in_sizes[2];       // 3200

    float* probsT = (float*)d_ws;                                     // 422 KB
    float* vout   = (float*)((char*)d_ws + (size_t)16 * 1024 * 1024); // 122.9 MB

    {
        int tpb = 256;
        int blocks = (N + tpb - 1) / tpb;
        softmax_probsT_kernel<<<blocks, tpb, 0, stream>>>(class_logits, probsT, N);
    }

    dim3 grid((T / 4 + TPB - 1) / TPB, N / (NPT * RB));

    // Diagnostics -> workspace. Natural regalloc (NO launch_bounds): R5 showed
    // a min-waves clamp manufactures spills (VGPR 48, ~1GB phantom traffic).
    if (ws_size >= (size_t)160 * 1024 * 1024) {
        cost_diag<1, 2><<<grid, TPB, 0, stream>>>(probsT, bbox_coords,
            target_labels, target_boxes, vout, N, T);   // full math x2
        cost_diag<2, 6><<<grid, TPB, 0, stream>>>(probsT, bbox_coords,
            target_labels, target_boxes, vout, N, T);   // store-only x6
    }

    // Kernel of record — bit-identical to R6.
    cost_matrix_kernel<<<grid, TPB, 0, stream>>>(probsT, bbox_coords,
        target_labels, target_boxes, out, N, T);
}

// Round 8
// 244.803 us; speedup vs baseline: 1.3400x; 1.3400x over previous
//
#include <hip/hip_runtime.h>

#define COST_CLASS 1.0f
#define COST_BBOX  5.0f
#define COST_GIOU  2.0f
#define EPS 1e-6f

// Problem constants (from setup_inputs): B=32, Q=300, C=11, T=3200
constexpr int kC  = 11;
constexpr int TPB = 64;    // 1 wave per block (800 t4 groups -> 13 blocks/row)
constexpr int NPT = 8;     // preds per inner chunk
constexpr int RB  = 4;     // row-blocks per thread -> 32 preds/thread

typedef float vf4 __attribute__((ext_vector_type(4)));
typedef float vf8 __attribute__((ext_vector_type(8)));

__device__ __forceinline__ float fast_rcp(float x) {
    return __builtin_amdgcn_rcpf(x);   // v_rcp_f32, ~1 ulp — fine vs 0.4 absmax threshold
}

// ---------------- Kernel A: softmax -> TRANSPOSED, pre-folded class cost ----
// probsT[c][n] = 2 - softmax(logits[n])[c]; the 2 folds the GIoU identity
//   (carea-uni)/(carea+EPS) == 1 - (uni+EPS)/(carea+EPS).
__global__ void softmax_probsT_kernel(const float* __restrict__ logits,
                                      float* __restrict__ probsT, int N) {
    int n = blockIdx.x * blockDim.x + threadIdx.x;
    if (n >= N) return;
    float v[kC];
    float m = -1e30f;
#pragma unroll
    for (int c = 0; c < kC; ++c) {
        v[c] = logits[n * kC + c];
        m = fmaxf(m, v[c]);
    }
    float s = 0.f;
#pragma unroll
    for (int c = 0; c < kC; ++c) {
        v[c] = __expf(v[c] - m);
        s += v[c];
    }
    float inv = fast_rcp(s);
#pragma unroll
    for (int c = 0; c < kC; ++c)
        probsT[(size_t)c * N + n] = fmaf(-v[c], inv, 2.0f);   // 2 - prob
}

// ---------------- Kernel B: production cost matrix (bit-identical to R6) ----
__global__ void cost_matrix_kernel(const float* __restrict__ probsT,      // [C,N] (=2-prob)
                                   const float* __restrict__ pred_boxes,  // [N,4] cxcywh
                                   const int*   __restrict__ labels,      // [T]
                                   const float* __restrict__ tboxes,      // [T,4] cxcywh
                                   float* __restrict__ out,               // [N,T]
                                   int N, int T) {
    int t4 = blockIdx.x * TPB + threadIdx.x;   // group of 4 targets
    if (t4 >= (T >> 2)) return;
    int tbase = t4 << 2;

    int4 labv = ((const int4*)labels)[t4];
    const int labs[4] = {labv.x, labv.y, labv.z, labv.w};
    float4 tb[4];
    float tx0[4], ty0[4], tx1[4], ty1[4], tarea[4];
#pragma unroll
    for (int j = 0; j < 4; ++j) {
        tb[j] = ((const float4*)tboxes)[tbase + j];
        tx0[j] = tb[j].x - 0.5f * tb[j].z;
        ty0[j] = tb[j].y - 0.5f * tb[j].w;
        tx1[j] = tb[j].x + 0.5f * tb[j].z;
        ty1[j] = tb[j].y + 0.5f * tb[j].w;
        tarea[j] = (tx1[j] - tx0[j]) * (ty1[j] - ty0[j]);
    }

#pragma unroll 1
    for (int rb = 0; rb < RB; ++rb) {
        int n0 = blockIdx.y * (NPT * RB) + rb * NPT;
        vf8 ccv[4];
#pragma unroll
        for (int j = 0; j < 4; ++j)
            ccv[j] = *(const vf8*)(probsT + (size_t)labs[j] * N + n0);

#pragma unroll
        for (int i = 0; i < NPT; ++i) {
            int n = n0 + i;
            float4 pb = ((const float4*)pred_boxes)[n];  // block-uniform -> s_load
            float p_x0 = pb.x - 0.5f * pb.z;
            float p_y0 = pb.y - 0.5f * pb.w;
            float p_x1 = pb.x + 0.5f * pb.z;
            float p_y1 = pb.y + 0.5f * pb.w;
            float p_area = (p_x1 - p_x0) * (p_y1 - p_y0);

            vf4 res;
#pragma unroll
            for (int j = 0; j < 4; ++j) {
                float cb = fabsf(pb.x - tb[j].x) + fabsf(pb.y - tb[j].y) +
                           fabsf(pb.z - tb[j].z) + fabsf(pb.w - tb[j].w);
                float lt_x = fmaxf(p_x0, tx0[j]), lt_y = fmaxf(p_y0, ty0[j]);
                float rb_x = fminf(p_x1, tx1[j]), rb_y = fminf(p_y1, ty1[j]);
                float iw = fmaxf(rb_x - lt_x, 0.f), ih = fmaxf(rb_y - lt_y, 0.f);
                float inter = iw * ih;
                float u = p_area + tarea[j] - inter + EPS;   // union + EPS
                float iou = inter * fast_rcp(u);
                float cx0 = fminf(p_x0, tx0[j]), cy0 = fminf(p_y0, ty0[j]);
                float cx1 = fmaxf(p_x1, tx1[j]), cy1 = fmaxf(p_y1, ty1[j]);
                float carea = (cx1 - cx0) * (cy1 - cy0);
                float g = u * fast_rcp(carea + EPS);         // (uni+EPS)/(carea+EPS)
                float rr = fmaf(COST_BBOX, cb, ccv[j][i]);
                rr = fmaf(-2.0f, iou, rr);
                res[j] = fmaf(-2.0f, g, rr);
            }
            *(vf4*)(out + (size_t)n * T + tbase) = res;
        }
    }
}

// ---------------- Diagnostic: exact clone x3, DISJOINT row rotation ---------
// R7's bug: rotation by 8 rows -> 75% of pass-1 writes hit pass-0's dirty L2
// lines -> per-pass time != production time. Fix: rotate by N/3 = 3200 rows,
// all 3 passes write fully disjoint rows. Sanity: WRITE_SIZE must be ~360000KB.
// Per-pass = dur/3 = production time EXACTLY (same code, same write behavior).
__global__ void cost_matrix_clone3(const float* __restrict__ probsT,
                                   const float* __restrict__ pred_boxes,
                                   const int*   __restrict__ labels,
                                   const float* __restrict__ tboxes,
                                   float* __restrict__ out, int N, int T) {
    int t4 = blockIdx.x * TPB + threadIdx.x;
    if (t4 >= (T >> 2)) return;
    int tbase = t4 << 2;

    int4 labv = ((const int4*)labels)[t4];
    const int labs[4] = {labv.x, labv.y, labv.z, labv.w};
    float4 tb[4];
    float tx0[4], ty0[4], tx1[4], ty1[4], tarea[4];
#pragma unroll
    for (int j = 0; j < 4; ++j) {
        tb[j] = ((const float4*)tboxes)[tbase + j];
        tx0[j] = tb[j].x - 0.5f * tb[j].z;
        ty0[j] = tb[j].y - 0.5f * tb[j].w;
        tx1[j] = tb[j].x + 0.5f * tb[j].z;
        ty1[j] = tb[j].y + 0.5f * tb[j].w;
        tarea[j] = (tx1[j] - tx0[j]) * (ty1[j] - ty0[j]);
    }

#pragma unroll 1
    for (int r = 0; r < 3; ++r) {
        int rshift = r * (N / 3);              // 0, 3200, 6400: disjoint rows
#pragma unroll 1
        for (int rb = 0; rb < RB; ++rb) {
            int n0 = blockIdx.y * (NPT * RB) + rb * NPT;
            vf8 ccv[4];
#pragma unroll
            for (int j = 0; j < 4; ++j)
                ccv[j] = *(const vf8*)(probsT + (size_t)labs[j] * N + n0);

#pragma unroll
            for (int i = 0; i < NPT; ++i) {
                int n = n0 + i;
                float4 pb = ((const float4*)pred_boxes)[n];
                pb.x += (float)r * 1e-20f;     // per-pass CSE breaker
                float p_x0 = pb.x - 0.5f * pb.z;
                float p_y0 = pb.y - 0.5f * pb.w;
                float p_x1 = pb.x + 0.5f * pb.z;
                float p_y1 = pb.y + 0.5f * pb.w;
                float p_area = (p_x1 - p_x0) * (p_y1 - p_y0);

                vf4 res;
#pragma unroll
                for (int j = 0; j < 4; ++j) {
                    float cb = fabsf(pb.x - tb[j].x) + fabsf(pb.y - tb[j].y) +
                               fabsf(pb.z - tb[j].z) + fabsf(pb.w - tb[j].w);
                    float lt_x = fmaxf(p_x0, tx0[j]), lt_y = fmaxf(p_y0, ty0[j]);
                    float rb_x = fminf(p_x1, tx1[j]), rb_y = fminf(p_y1, ty1[j]);
                    float iw = fmaxf(rb_x - lt_x, 0.f), ih = fmaxf(rb_y - lt_y, 0.f);
                    float inter = iw * ih;
                    float u = p_area + tarea[j] - inter + EPS;
                    float iou = inter * fast_rcp(u);
                    float cx0 = fminf(p_x0, tx0[j]), cy0 = fminf(p_y0, ty0[j]);
                    float cx1 = fmaxf(p_x1, tx1[j]), cy1 = fmaxf(p_y1, ty1[j]);
                    float carea = (cx1 - cx0) * (cy1 - cy0);
                    float g = u * fast_rcp(carea + EPS);
                    float rr = fmaf(COST_BBOX, cb, ccv[j][i]);
                    rr = fmaf(-2.0f, iou, rr);
                    res[j] = fmaf(-2.0f, g, rr);
                }
                int nn = n + rshift;
                if (nn >= N) nn -= N;
                *(vf4*)(out + (size_t)nn * T + tbase) = res;
            }
        }
    }
}

extern "C" void kernel_launch(void* const* d_in, const int* in_sizes, int n_in,
                              void* d_out, int out_size, void* d_ws, size_t ws_size,
                              hipStream_t stream) {
    const float* class_logits  = (const float*)d_in[0];  // [B,Q,C]
    const float* bbox_coords   = (const float*)d_in[1];  // [B,Q,4]
    const int*   target_labels = (const int*)d_in[2];    // [T]
    const float* target_boxes  = (const float*)d_in[3];  // [T,4]
    float* out = (float*)d_out;

    int N = in_sizes[0] / kC;  // 9600
    int T = in_sizes[2];       // 3200

    float* probsT = (float*)d_ws;                                     // 422 KB
    float* vout   = (float*)((char*)d_ws + (size_t)16 * 1024 * 1024); // 122.9 MB

    {
        int tpb = 256;
        int blocks = (N + tpb - 1) / tpb;
        softmax_probsT_kernel<<<blocks, tpb, 0, stream>>>(class_logits, probsT, N);
    }

    dim3 grid((T / 4 + TPB - 1) / TPB, N / (NPT * RB));

    // Decisive diagnostic: 3x production clone, disjoint writes -> top-5 row
    // with the production structure's true VGPR/VALUBusy/Occupancy/FETCH.
    if (ws_size >= (size_t)160 * 1024 * 1024) {
        cost_matrix_clone3<<<grid, TPB, 0, stream>>>(probsT, bbox_coords,
            target_labels, target_boxes, vout, N, T);
    }

    // Kernel of record — bit-identical to R6.
    cost_matrix_kernel<<<grid, TPB, 0, stream>>>(probsT, bbox_coords,
        target_labels, target_boxes, out, N, T);
}